// Round 1
// baseline (434.221 us; speedup 1.0000x reference)
//
#include <hip/hip_runtime.h>

#define N_   8192
#define FIN  256
#define FOUT 128
#define BI   16
#define BJ   64

// Kernel 1: Wh = h @ W  (8192x256 @ 256x128), s1 = Wh@a1, s2 = Wh@a2.
// One block = 2 rows, 128 threads per row (thread c owns output col c).
__global__ __launch_bounds__(256) void k_wh(
    const float* __restrict__ h, const float* __restrict__ W,
    const float* __restrict__ a, float* __restrict__ Wh,
    float* __restrict__ s1, float* __restrict__ s2)
{
    __shared__ float hrow[2][FIN];
    __shared__ float rbuf[2][2][2];
    const int t   = threadIdx.x;
    const int rh  = t >> 7;        // 0..1 which row of the pair
    const int c   = t & 127;       // output column
    const int row = (blockIdx.x << 1) + rh;

    hrow[rh][c]       = h[(size_t)row * FIN + c];
    hrow[rh][c + 128] = h[(size_t)row * FIN + c + 128];
    __syncthreads();

    float acc = 0.f;
    #pragma unroll 8
    for (int k = 0; k < FIN; ++k)
        acc = fmaf(hrow[rh][k], W[k * FOUT + c], acc);

    Wh[(size_t)row * FOUT + c] = acc;

    float p1 = acc * a[c];
    float p2 = acc * a[FOUT + c];
    #pragma unroll
    for (int off = 32; off; off >>= 1) {
        p1 += __shfl_down(p1, off, 64);
        p2 += __shfl_down(p2, off, 64);
    }
    if ((t & 63) == 0) { rbuf[rh][c >> 6][0] = p1; rbuf[rh][c >> 6][1] = p2; }
    __syncthreads();
    if (c == 0) {
        s1[row] = rbuf[rh][0][0] + rbuf[rh][1][0];
        s2[row] = rbuf[rh][0][1] + rbuf[rh][1][1];
    }
}

// Kernel 2: fused masked-softmax attention + (attention @ Wh).
// Block = 256 threads, BI=16 output rows. Loop over j in tiles of BJ=64:
//   stage Wh[jb:jb+64][128] in LDS, compute p[i][j] = adj ? exp(lrelu(s1+s2)) : 0,
//   accumulate num (2 rows x 4 cols per thread in registers) and den.
// No max-subtraction needed: |s1+s2| <~ 12 so exp() stays in fp32 range and
// num/den is scale-invariant.
__global__ __launch_bounds__(256) void k_attn(
    const int* __restrict__ adj, const float* __restrict__ Wh,
    const float* __restrict__ s1g, const float* __restrict__ s2g,
    float* __restrict__ out)
{
    __shared__ float whs[BJ][FOUT];       // 32 KB
    __shared__ float ps[BI][BJ + 4];      // padded to keep float4 alignment
    __shared__ float dens[BI];

    const int t     = threadIdx.x;
    const int rbase = blockIdx.x * BI;

    // p-compute mapping: thread owns row pr, 4 j's starting at pj
    const int pr = t >> 4;                // 0..15
    const int pj = (t & 15) << 2;         // 0..60
    const float s1r = s1g[rbase + pr];

    // accumulate mapping: thread owns rows {2rp, 2rp+1} x cols [cg, cg+4)
    const int rp = t >> 5;                // 0..7
    const int cg = (t & 31) << 2;         // 0..124

    float4 acc0 = {0.f, 0.f, 0.f, 0.f};
    float4 acc1 = {0.f, 0.f, 0.f, 0.f};
    float denp = 0.f;

    const float4* __restrict__ whg = (const float4*)Wh;

    for (int jb = 0; jb < N_; jb += BJ) {
        __syncthreads();   // protect whs/ps from previous iteration's readers

        // stage Wh tile: 64*128 floats = 2048 float4, 8 per thread, coalesced
        #pragma unroll
        for (int q = 0; q < 8; ++q) {
            int i4 = q * 256 + t;
            ((float4*)&whs[0][0])[i4] = whg[jb * (FOUT / 4) + i4];
        }

        // adj tile + attention weights
        int4   av  = *(const int4*)&adj[(size_t)(rbase + pr) * N_ + jb + pj];
        float4 s2v = *(const float4*)&s2g[jb + pj];
        float4 pq;
        float e;
        e = s1r + s2v.x; e = e > 0.f ? e : 0.2f * e; pq.x = av.x ? __expf(e) : 0.f;
        e = s1r + s2v.y; e = e > 0.f ? e : 0.2f * e; pq.y = av.y ? __expf(e) : 0.f;
        e = s1r + s2v.z; e = e > 0.f ? e : 0.2f * e; pq.z = av.z ? __expf(e) : 0.f;
        e = s1r + s2v.w; e = e > 0.f ? e : 0.2f * e; pq.w = av.w ? __expf(e) : 0.f;
        *(float4*)&ps[pr][pj] = pq;
        denp += pq.x + pq.y + pq.z + pq.w;

        __syncthreads();

        const float* __restrict__ p0r = &ps[2 * rp][0];
        const float* __restrict__ p1r = &ps[2 * rp + 1][0];
        #pragma unroll 4
        for (int j = 0; j < BJ; ++j) {
            float p0 = p0r[j];
            float p1 = p1r[j];
            float4 w = *(const float4*)&whs[j][cg];
            acc0.x = fmaf(p0, w.x, acc0.x);
            acc0.y = fmaf(p0, w.y, acc0.y);
            acc0.z = fmaf(p0, w.z, acc0.z);
            acc0.w = fmaf(p0, w.w, acc0.w);
            acc1.x = fmaf(p1, w.x, acc1.x);
            acc1.y = fmaf(p1, w.y, acc1.y);
            acc1.z = fmaf(p1, w.z, acc1.z);
            acc1.w = fmaf(p1, w.w, acc1.w);
        }
    }

    // den: lanes [16r, 16r+15] hold partials for row r (same row all tiles)
    #pragma unroll
    for (int off = 8; off; off >>= 1) denp += __shfl_down(denp, off, 16);
    if ((t & 15) == 0) dens[pr] = denp;
    __syncthreads();

    const float inv0 = 1.f / dens[2 * rp];
    const float inv1 = 1.f / dens[2 * rp + 1];
    float4 o0 = { acc0.x * inv0, acc0.y * inv0, acc0.z * inv0, acc0.w * inv0 };
    float4 o1 = { acc1.x * inv1, acc1.y * inv1, acc1.z * inv1, acc1.w * inv1 };
    *(float4*)&out[(size_t)(rbase + 2 * rp)     * FOUT + cg] = o0;
    *(float4*)&out[(size_t)(rbase + 2 * rp + 1) * FOUT + cg] = o1;
}

extern "C" void kernel_launch(void* const* d_in, const int* in_sizes, int n_in,
                              void* d_out, int out_size, void* d_ws, size_t ws_size,
                              hipStream_t stream) {
    const float* h   = (const float*)d_in[0];
    const int*   adj = (const int*)d_in[1];
    const float* W   = (const float*)d_in[2];
    const float* a   = (const float*)d_in[3];
    float* out = (float*)d_out;

    float* Wh = (float*)d_ws;                 // 8192*128 f32 = 4 MB
    float* s1 = Wh + (size_t)N_ * FOUT;       // 32 KB
    float* s2 = s1 + N_;                      // 32 KB

    k_wh  <<<N_ / 2,  256, 0, stream>>>(h, W, a, Wh, s1, s2);
    k_attn<<<N_ / BI, 256, 0, stream>>>(adj, Wh, s1, s2, out);
}

// Round 2
// 434.011 us; speedup vs baseline: 1.0005x; 1.0005x over previous
//
#include <hip/hip_runtime.h>

#define N_   8192
#define FIN  256
#define FOUT 128
#define BI   16
#define BJ   64

// Kernel 1: Wh = h @ W  (8192x256 @ 256x128), s1 = Wh@a1, s2 = Wh@a2.
// One block = 2 rows, 128 threads per row (thread c owns output col c).
__global__ __launch_bounds__(256) void k_wh(
    const float* __restrict__ h, const float* __restrict__ W,
    const float* __restrict__ a, float* __restrict__ Wh,
    float* __restrict__ s1, float* __restrict__ s2)
{
    __shared__ float hrow[2][FIN];
    __shared__ float rbuf[2][2][2];
    const int t   = threadIdx.x;
    const int rh  = t >> 7;        // 0..1 which row of the pair
    const int c   = t & 127;       // output column
    const int row = (blockIdx.x << 1) + rh;

    hrow[rh][c]       = h[(size_t)row * FIN + c];
    hrow[rh][c + 128] = h[(size_t)row * FIN + c + 128];
    __syncthreads();

    float acc = 0.f;
    #pragma unroll 8
    for (int k = 0; k < FIN; ++k)
        acc = fmaf(hrow[rh][k], W[k * FOUT + c], acc);

    Wh[(size_t)row * FOUT + c] = acc;

    float p1 = acc * a[c];
    float p2 = acc * a[FOUT + c];
    #pragma unroll
    for (int off = 32; off; off >>= 1) {
        p1 += __shfl_down(p1, off, 64);
        p2 += __shfl_down(p2, off, 64);
    }
    if ((t & 63) == 0) { rbuf[rh][c >> 6][0] = p1; rbuf[rh][c >> 6][1] = p2; }
    __syncthreads();
    if (c == 0) {
        s1[row] = rbuf[rh][0][0] + rbuf[rh][1][0];
        s2[row] = rbuf[rh][0][1] + rbuf[rh][1][1];
    }
}

// Kernel 2: fused masked-softmax attention + (attention @ Wh).
// Block = 256 threads, BI=16 output rows. Loop over j in tiles of BJ=64:
//   stage Wh[jb:jb+64][128] in LDS, compute p[i][j] = adj ? exp(lrelu(s1+s2)) : 0,
//   accumulate num (2 rows x 4 cols per thread in registers) and den.
// No max-subtraction needed: |s1+s2| <~ 12 so exp() stays in fp32 range and
// num/den is scale-invariant.
__global__ __launch_bounds__(256) void k_attn(
    const int* __restrict__ adj, const float* __restrict__ Wh,
    const float* __restrict__ s1g, const float* __restrict__ s2g,
    float* __restrict__ out)
{
    __shared__ float whs[BJ][FOUT];       // 32 KB
    __shared__ float ps[BI][BJ + 4];      // padded to keep float4 alignment
    __shared__ float dens[BI];

    const int t     = threadIdx.x;
    const int rbase = blockIdx.x * BI;

    // p-compute mapping: thread owns row pr, 4 j's starting at pj
    const int pr = t >> 4;                // 0..15
    const int pj = (t & 15) << 2;         // 0..60
    const float s1r = s1g[rbase + pr];

    // accumulate mapping: thread owns rows {2rp, 2rp+1} x cols [cg, cg+4)
    const int rp = t >> 5;                // 0..7
    const int cg = (t & 31) << 2;         // 0..124

    float4 acc0 = {0.f, 0.f, 0.f, 0.f};
    float4 acc1 = {0.f, 0.f, 0.f, 0.f};
    float denp = 0.f;

    const float4* __restrict__ whg = (const float4*)Wh;

    for (int jb = 0; jb < N_; jb += BJ) {
        __syncthreads();   // protect whs/ps from previous iteration's readers

        // stage Wh tile: 64*128 floats = 2048 float4, 8 per thread, coalesced
        #pragma unroll
        for (int q = 0; q < 8; ++q) {
            int i4 = q * 256 + t;
            ((float4*)&whs[0][0])[i4] = whg[jb * (FOUT / 4) + i4];
        }

        // adj tile + attention weights
        int4   av  = *(const int4*)&adj[(size_t)(rbase + pr) * N_ + jb + pj];
        float4 s2v = *(const float4*)&s2g[jb + pj];
        float4 pq;
        float e;
        e = s1r + s2v.x; e = e > 0.f ? e : 0.2f * e; pq.x = av.x ? __expf(e) : 0.f;
        e = s1r + s2v.y; e = e > 0.f ? e : 0.2f * e; pq.y = av.y ? __expf(e) : 0.f;
        e = s1r + s2v.z; e = e > 0.f ? e : 0.2f * e; pq.z = av.z ? __expf(e) : 0.f;
        e = s1r + s2v.w; e = e > 0.f ? e : 0.2f * e; pq.w = av.w ? __expf(e) : 0.f;
        *(float4*)&ps[pr][pj] = pq;
        denp += pq.x + pq.y + pq.z + pq.w;

        __syncthreads();

        const float* __restrict__ p0r = &ps[2 * rp][0];
        const float* __restrict__ p1r = &ps[2 * rp + 1][0];
        #pragma unroll 4
        for (int j = 0; j < BJ; ++j) {
            float p0 = p0r[j];
            float p1 = p1r[j];
            float4 w = *(const float4*)&whs[j][cg];
            acc0.x = fmaf(p0, w.x, acc0.x);
            acc0.y = fmaf(p0, w.y, acc0.y);
            acc0.z = fmaf(p0, w.z, acc0.z);
            acc0.w = fmaf(p0, w.w, acc0.w);
            acc1.x = fmaf(p1, w.x, acc1.x);
            acc1.y = fmaf(p1, w.y, acc1.y);
            acc1.z = fmaf(p1, w.z, acc1.z);
            acc1.w = fmaf(p1, w.w, acc1.w);
        }
    }

    // den: lanes [16r, 16r+15] hold partials for row r (same row all tiles)
    #pragma unroll
    for (int off = 8; off; off >>= 1) denp += __shfl_down(denp, off, 16);
    if ((t & 15) == 0) dens[pr] = denp;
    __syncthreads();

    const float inv0 = 1.f / dens[2 * rp];
    const float inv1 = 1.f / dens[2 * rp + 1];
    float4 o0 = { acc0.x * inv0, acc0.y * inv0, acc0.z * inv0, acc0.w * inv0 };
    float4 o1 = { acc1.x * inv1, acc1.y * inv1, acc1.z * inv1, acc1.w * inv1 };
    *(float4*)&out[(size_t)(rbase + 2 * rp)     * FOUT + cg] = o0;
    *(float4*)&out[(size_t)(rbase + 2 * rp + 1) * FOUT + cg] = o1;
}

extern "C" void kernel_launch(void* const* d_in, const int* in_sizes, int n_in,
                              void* d_out, int out_size, void* d_ws, size_t ws_size,
                              hipStream_t stream) {
    const float* h   = (const float*)d_in[0];
    const int*   adj = (const int*)d_in[1];
    const float* W   = (const float*)d_in[2];
    const float* a   = (const float*)d_in[3];
    float* out = (float*)d_out;

    float* Wh = (float*)d_ws;                 // 8192*128 f32 = 4 MB
    float* s1 = Wh + (size_t)N_ * FOUT;       // 32 KB
    float* s2 = s1 + N_;                      // 32 KB

    k_wh  <<<N_ / 2,  256, 0, stream>>>(h, W, a, Wh, s1, s2);
    k_attn<<<N_ / BI, 256, 0, stream>>>(adj, Wh, s1, s2, out);
}

// Round 3
// 145.362 us; speedup vs baseline: 2.9872x; 2.9857x over previous
//
#include <hip/hip_runtime.h>

#define N_   8192
#define FIN  256
#define FOUT 128

typedef _Float16 f16x8 __attribute__((ext_vector_type(8)));
typedef _Float16 f16x4 __attribute__((ext_vector_type(4)));
typedef float    f32x4 __attribute__((ext_vector_type(4)));

// ---------------- Kernel 1: Wh = h @ W, s1 = Wh@a1, s2 = Wh@a2 ----------------
__global__ __launch_bounds__(256) void k_wh(
    const float* __restrict__ h, const float* __restrict__ W,
    const float* __restrict__ a, float* __restrict__ Wh,
    float* __restrict__ s1, float* __restrict__ s2)
{
    __shared__ float hrow[2][FIN];
    __shared__ float rbuf[2][2][2];
    const int t   = threadIdx.x;
    const int rh  = t >> 7;
    const int c   = t & 127;
    const int row = (blockIdx.x << 1) + rh;

    hrow[rh][c]       = h[(size_t)row * FIN + c];
    hrow[rh][c + 128] = h[(size_t)row * FIN + c + 128];
    __syncthreads();

    float acc = 0.f;
    #pragma unroll 8
    for (int k = 0; k < FIN; ++k)
        acc = fmaf(hrow[rh][k], W[k * FOUT + c], acc);

    Wh[(size_t)row * FOUT + c] = acc;

    float p1 = acc * a[c];
    float p2 = acc * a[FOUT + c];
    #pragma unroll
    for (int off = 32; off; off >>= 1) {
        p1 += __shfl_down(p1, off, 64);
        p2 += __shfl_down(p2, off, 64);
    }
    if ((t & 63) == 0) { rbuf[rh][c >> 6][0] = p1; rbuf[rh][c >> 6][1] = p2; }
    __syncthreads();
    if (c == 0) {
        s1[row] = rbuf[rh][0][0] + rbuf[rh][1][0];
        s2[row] = rbuf[rh][0][1] + rbuf[rh][1][1];
    }
}

// ---------------- Kernel 2: transpose+convert Wh -> WhT fp16 [128][8192] ------
__global__ __launch_bounds__(256) void k_tr(
    const float* __restrict__ Wh, _Float16* __restrict__ WhT)
{
    __shared__ float tile[64][129];
    const int t = threadIdx.x;
    const int rbase = blockIdx.x * 64;

    #pragma unroll
    for (int q = 0; q < 8; ++q) {
        int i4 = q * 256 + t;
        int r  = i4 >> 5;
        int c4 = (i4 & 31) * 4;
        *(float4*)&tile[r][c4] = *(const float4*)&Wh[(size_t)(rbase + r) * FOUT + c4];
    }
    __syncthreads();

    const int c = t >> 1, half = t & 1;
    _Float16 buf[32];
    #pragma unroll
    for (int r = 0; r < 32; ++r) buf[r] = (_Float16)tile[32 * half + r][c];
    #pragma unroll
    for (int q = 0; q < 4; ++q)
        *(f16x8*)&WhT[(size_t)c * N_ + rbase + 32 * half + 8 * q] = *(f16x8*)&buf[8 * q];
}

// ---------------- Kernel 3: fused masked-softmax numerator (MFMA) -------------
// Grid: 1024 blocks = 256 row-blocks (BI=32) x 4 j-splits (2048 j each).
// Block: 512 thr = 8 waves; wave w owns cols [16w,16w+16), row-frags rf=0,1.
// Per j-tile (BJ=64): compute P=adj?exp(lrelu(s1+s2)-4):0 in fp16 into
// swizzled LDS, then 4 MFMA (16x16x32_f16) per wave. B-frags read directly
// from L2-resident WhT. Writes unnormalized num + den partials to ws.
__global__ __launch_bounds__(512, 4) void k_attn(
    const int* __restrict__ adj, const _Float16* __restrict__ WhT,
    const float* __restrict__ s1g, const float* __restrict__ s2g,
    float* __restrict__ num_g, float* __restrict__ den_g)
{
    __shared__ _Float16 pA[32 * 64];   // 4 KB, XOR-swizzled

    const int t  = threadIdx.x;
    const int w  = t >> 6;             // wave 0..7 = col-frag
    const int l  = t & 63;             // lane

    const int rb    = blockIdx.x & 255;
    const int sp    = blockIdx.x >> 8;
    const int rbase = rb * 32;
    const int jbase = sp * 2048;
    const int NT    = 2048 / 64;

    // p-compute mapping: thread owns row r, 4 cols at j0
    const int r  = t >> 4;
    const int j0 = (t & 15) << 2;
    const float s1r = s1g[rbase + r];
    const int* __restrict__ adjrow = adj + (size_t)(rbase + r) * N_;

    // MFMA operand addressing
    const int ln15 = l & 15, lq = l >> 4;
    const _Float16* __restrict__ bptr =
        WhT + (size_t)(16 * w + ln15) * N_ + 8 * lq;
    const int a_row0 = ln15;           // rf=0 row
    const int a_row1 = 16 + ln15;      // rf=1 row
    const int a_sw0  = (a_row0 & 7) << 3;
    const int a_sw1  = (a_row1 & 7) << 3;

    f32x4 acc0 = {0.f, 0.f, 0.f, 0.f};
    f32x4 acc1 = {0.f, 0.f, 0.f, 0.f};
    float denp = 0.f;

    // prefetch tile 0
    int4   av  = *(const int4*)(adjrow + jbase + j0);
    float4 s2v = *(const float4*)(s2g + jbase + j0);

    for (int tile = 0; tile < NT; ++tile) {
        const int jb = jbase + tile * 64;

        // ---- phase A: p-compute -> LDS (fp16) + den accum ----
        float e, p0, p1, p2, p3;
        e = s1r + s2v.x; e = e > 0.f ? e : 0.2f * e; p0 = av.x ? __expf(e - 4.f) : 0.f;
        e = s1r + s2v.y; e = e > 0.f ? e : 0.2f * e; p1 = av.y ? __expf(e - 4.f) : 0.f;
        e = s1r + s2v.z; e = e > 0.f ? e : 0.2f * e; p2 = av.z ? __expf(e - 4.f) : 0.f;
        e = s1r + s2v.w; e = e > 0.f ? e : 0.2f * e; p3 = av.w ? __expf(e - 4.f) : 0.f;
        _Float16 h0 = (_Float16)p0, h1 = (_Float16)p1,
                 h2 = (_Float16)p2, h3 = (_Float16)p3;
        denp += (float)h0 + (float)h1 + (float)h2 + (float)h3;
        f16x4 pv = {h0, h1, h2, h3};
        *(f16x4*)(pA + r * 64 + (j0 ^ ((r & 7) << 3))) = pv;

        __syncthreads();

        // ---- prefetch next tile's adj/s2 under MFMA phase ----
        const int jn = (tile + 1 < NT) ? jb + 64 : jbase;
        int4   av_n  = *(const int4*)(adjrow + jn + j0);
        float4 s2v_n = *(const float4*)(s2g + jn + j0);

        // ---- phase B: B-frags from global (L2), A-frags from LDS, 4 MFMA ----
        f16x8 b0 = *(const f16x8*)(bptr + jb);
        f16x8 b1 = *(const f16x8*)(bptr + jb + 32);

        f16x8 a00 = *(const f16x8*)(pA + a_row0 * 64 + ((8 * lq)      ^ a_sw0));
        f16x8 a01 = *(const f16x8*)(pA + a_row0 * 64 + ((32 + 8 * lq) ^ a_sw0));
        f16x8 a10 = *(const f16x8*)(pA + a_row1 * 64 + ((8 * lq)      ^ a_sw1));
        f16x8 a11 = *(const f16x8*)(pA + a_row1 * 64 + ((32 + 8 * lq) ^ a_sw1));

        acc0 = __builtin_amdgcn_mfma_f32_16x16x32_f16(a00, b0, acc0, 0, 0, 0);
        acc0 = __builtin_amdgcn_mfma_f32_16x16x32_f16(a01, b1, acc0, 0, 0, 0);
        acc1 = __builtin_amdgcn_mfma_f32_16x16x32_f16(a10, b0, acc1, 0, 0, 0);
        acc1 = __builtin_amdgcn_mfma_f32_16x16x32_f16(a11, b1, acc1, 0, 0, 0);

        __syncthreads();
        av = av_n; s2v = s2v_n;
    }

    // ---- den: reduce 16 lanes per row (t&15 groups are lane groups) ----
    denp += __shfl_xor(denp, 1, 64);
    denp += __shfl_xor(denp, 2, 64);
    denp += __shfl_xor(denp, 4, 64);
    denp += __shfl_xor(denp, 8, 64);
    if ((t & 15) == 0)
        den_g[(size_t)sp * N_ + rbase + r] = denp;

    // ---- num: unnormalized partial writes ----
    const int colg = 16 * w + ln15;
    const int rq   = lq * 4;
    #pragma unroll
    for (int q = 0; q < 4; ++q) {
        num_g[((size_t)sp * N_ + rbase + rq + q)      * FOUT + colg] = acc0[q];
        num_g[((size_t)sp * N_ + rbase + 16 + rq + q) * FOUT + colg] = acc1[q];
    }
}

// ---------------- Kernel 4: combine j-splits and normalize --------------------
__global__ __launch_bounds__(256) void k_norm(
    const float* __restrict__ num_g, const float* __restrict__ den_g,
    float* __restrict__ out)
{
    const int idx4 = blockIdx.x * 256 + threadIdx.x;  // 262144 float4s
    const int i  = idx4 >> 5;
    const int c4 = (idx4 & 31) * 4;

    float4 s = {0.f, 0.f, 0.f, 0.f};
    float  d = 0.f;
    #pragma unroll
    for (int sp = 0; sp < 4; ++sp) {
        float4 v = *(const float4*)(num_g + ((size_t)sp * N_ + i) * FOUT + c4);
        s.x += v.x; s.y += v.y; s.z += v.z; s.w += v.w;
        d += den_g[(size_t)sp * N_ + i];
    }
    const float inv = 1.f / d;
    float4 o = {s.x * inv, s.y * inv, s.z * inv, s.w * inv};
    *(float4*)&out[(size_t)i * FOUT + c4] = o;
}

extern "C" void kernel_launch(void* const* d_in, const int* in_sizes, int n_in,
                              void* d_out, int out_size, void* d_ws, size_t ws_size,
                              hipStream_t stream) {
    const float* h   = (const float*)d_in[0];
    const int*   adj = (const int*)d_in[1];
    const float* W   = (const float*)d_in[2];
    const float* a   = (const float*)d_in[3];
    float* out = (float*)d_out;

    char* ws = (char*)d_ws;
    float*    Wh  = (float*)ws;                           // 4 MB
    _Float16* WhT = (_Float16*)(ws + (4u << 20));         // 2 MB
    float*    s1  = (float*)(ws + (6u << 20));            // 32 KB
    float*    s2  = (float*)(ws + (6u << 20) + 32768);    // 32 KB
    float*    num = (float*)(ws + (7u << 20));            // 16 MB
    float*    den = (float*)(ws + (23u << 20));           // 128 KB

    k_wh  <<<N_ / 2, 256, 0, stream>>>(h, W, a, Wh, s1, s2);
    k_tr  <<<N_ / 64, 256, 0, stream>>>(Wh, WhT);
    k_attn<<<1024, 512, 0, stream>>>(adj, WhT, s1, s2, num, den);
    k_norm<<<1024, 256, 0, stream>>>(num, den, out);
}

// Round 4
// 132.209 us; speedup vs baseline: 3.2844x; 1.0995x over previous
//
#include <hip/hip_runtime.h>

#define N_   8192
#define FIN  256
#define FOUT 128

typedef _Float16 f16x8 __attribute__((ext_vector_type(8)));
typedef _Float16 f16x4 __attribute__((ext_vector_type(4)));
typedef float    f32x4 __attribute__((ext_vector_type(4)));

// ---------------- Kernel 1: Wh = h @ W, s1 = Wh@a1, s2 = Wh@a2 ----------------
__global__ __launch_bounds__(256) void k_wh(
    const float* __restrict__ h, const float* __restrict__ W,
    const float* __restrict__ a, float* __restrict__ Wh,
    float* __restrict__ s1, float* __restrict__ s2)
{
    __shared__ float hrow[2][FIN];
    __shared__ float rbuf[2][2][2];
    const int t   = threadIdx.x;
    const int rh  = t >> 7;
    const int c   = t & 127;
    const int row = (blockIdx.x << 1) + rh;

    hrow[rh][c]       = h[(size_t)row * FIN + c];
    hrow[rh][c + 128] = h[(size_t)row * FIN + c + 128];
    __syncthreads();

    float acc = 0.f;
    #pragma unroll 8
    for (int k = 0; k < FIN; ++k)
        acc = fmaf(hrow[rh][k], W[k * FOUT + c], acc);

    Wh[(size_t)row * FOUT + c] = acc;

    float p1 = acc * a[c];
    float p2 = acc * a[FOUT + c];
    #pragma unroll
    for (int off = 32; off; off >>= 1) {
        p1 += __shfl_down(p1, off, 64);
        p2 += __shfl_down(p2, off, 64);
    }
    if ((t & 63) == 0) { rbuf[rh][c >> 6][0] = p1; rbuf[rh][c >> 6][1] = p2; }
    __syncthreads();
    if (c == 0) {
        s1[row] = rbuf[rh][0][0] + rbuf[rh][1][0];
        s2[row] = rbuf[rh][0][1] + rbuf[rh][1][1];
    }
}

// ---------------- Kernel 2: transpose+convert Wh -> WhT fp16 [128][8192] ------
__global__ __launch_bounds__(256) void k_tr(
    const float* __restrict__ Wh, _Float16* __restrict__ WhT)
{
    __shared__ float tile[64][129];
    const int t = threadIdx.x;
    const int rbase = blockIdx.x * 64;

    #pragma unroll
    for (int q = 0; q < 8; ++q) {
        int i4 = q * 256 + t;
        int r  = i4 >> 5;
        int c4 = (i4 & 31) * 4;
        *(float4*)&tile[r][c4] = *(const float4*)&Wh[(size_t)(rbase + r) * FOUT + c4];
    }
    __syncthreads();

    const int c = t >> 1, half = t & 1;
    _Float16 buf[32];
    #pragma unroll
    for (int r = 0; r < 32; ++r) buf[r] = (_Float16)tile[32 * half + r][c];
    #pragma unroll
    for (int q = 0; q < 4; ++q)
        *(f16x8*)&WhT[(size_t)c * N_ + rbase + 32 * half + 8 * q] = *(f16x8*)&buf[8 * q];
}

// ---------------- Kernel 3: fused masked-softmax numerator (MFMA) -------------
// Grid: 1024 = 256 row-blocks (32 rows) x 4 j-splits (2048 j each).
// Block: 512 thr = 8 waves; wave w owns output cols [16w,16w+16).
// Per 128-j tile: ONE barrier. P double-buffered in LDS; adj prefetched 2 tiles
// ahead in named register slots (explicitly unrolled x2 loop).
__global__ __launch_bounds__(512, 4) void k_attn(
    const int* __restrict__ adj, const _Float16* __restrict__ WhT,
    const float* __restrict__ s1g, const float* __restrict__ s2g,
    float* __restrict__ num_g, float* __restrict__ den_g)
{
    __shared__ _Float16 pA[2][32][136];   // 17 KB, padded: 272 B row stride
    __shared__ float s2s[2048];           // 8 KB

    const int t  = threadIdx.x;
    const int w  = t >> 6;
    const int l  = t & 63;

    const int rb    = blockIdx.x & 255;
    const int sp    = blockIdx.x >> 8;
    const int rbase = rb * 32;
    const int jbase = sp * 2048;

    // stage s2 slice (8 KB)
    *(float4*)&s2s[t * 4] = *(const float4*)&s2g[jbase + t * 4];

    // p-compute mapping: thread owns row r, 8 j's at j0
    const int r  = t >> 4;                 // 0..31
    const int j0 = (t & 15) << 3;          // 0..120
    const float s1r = s1g[rbase + r];
    const int* __restrict__ arow = adj + (size_t)(rbase + r) * N_ + jbase;

    // MFMA operand addressing
    const int ln15 = l & 15, lq = l >> 4;
    const _Float16* __restrict__ bptr =
        WhT + (size_t)(16 * w + ln15) * N_ + jbase + 8 * lq;

    f32x4 acc0 = {0.f, 0.f, 0.f, 0.f};
    f32x4 acc1 = {0.f, 0.f, 0.f, 0.f};
    float denp = 0.f;

    // phase-A: compute 8 attention weights -> fp16 LDS buffer `buf`
    auto computeP = [&](const int4& aA, const int4& aB, int tile, int buf) {
        const float* s2p = &s2s[tile * 128 + j0];
        float4 sA = *(const float4*)(s2p);
        float4 sB = *(const float4*)(s2p + 4);
        float m, e;
        f16x8 pv;
        m = s1r + sA.x; e = fmaxf(m, 0.2f * m); pv[0] = (_Float16)(aA.x ? __expf(e - 4.f) : 0.f);
        m = s1r + sA.y; e = fmaxf(m, 0.2f * m); pv[1] = (_Float16)(aA.y ? __expf(e - 4.f) : 0.f);
        m = s1r + sA.z; e = fmaxf(m, 0.2f * m); pv[2] = (_Float16)(aA.z ? __expf(e - 4.f) : 0.f);
        m = s1r + sA.w; e = fmaxf(m, 0.2f * m); pv[3] = (_Float16)(aA.w ? __expf(e - 4.f) : 0.f);
        m = s1r + sB.x; e = fmaxf(m, 0.2f * m); pv[4] = (_Float16)(aB.x ? __expf(e - 4.f) : 0.f);
        m = s1r + sB.y; e = fmaxf(m, 0.2f * m); pv[5] = (_Float16)(aB.y ? __expf(e - 4.f) : 0.f);
        m = s1r + sB.z; e = fmaxf(m, 0.2f * m); pv[6] = (_Float16)(aB.z ? __expf(e - 4.f) : 0.f);
        m = s1r + sB.w; e = fmaxf(m, 0.2f * m); pv[7] = (_Float16)(aB.w ? __expf(e - 4.f) : 0.f);
        denp += (float)pv[0] + (float)pv[1] + (float)pv[2] + (float)pv[3]
              + (float)pv[4] + (float)pv[5] + (float)pv[6] + (float)pv[7];
        *(f16x8*)&pA[buf][r][j0] = pv;
    };

    // phase-B: 8 MFMAs over one 128-j tile from LDS buffer `buf`
    auto mmaTile = [&](int buf, int jb) {
        f16x8 b0 = *(const f16x8*)(bptr + jb);
        f16x8 b1 = *(const f16x8*)(bptr + jb + 32);
        f16x8 b2 = *(const f16x8*)(bptr + jb + 64);
        f16x8 b3 = *(const f16x8*)(bptr + jb + 96);
        const _Float16* a0p = &pA[buf][ln15][8 * lq];
        const _Float16* a1p = &pA[buf][16 + ln15][8 * lq];
        acc0 = __builtin_amdgcn_mfma_f32_16x16x32_f16(*(const f16x8*)(a0p),      b0, acc0, 0, 0, 0);
        acc1 = __builtin_amdgcn_mfma_f32_16x16x32_f16(*(const f16x8*)(a1p),      b0, acc1, 0, 0, 0);
        acc0 = __builtin_amdgcn_mfma_f32_16x16x32_f16(*(const f16x8*)(a0p + 32), b1, acc0, 0, 0, 0);
        acc1 = __builtin_amdgcn_mfma_f32_16x16x32_f16(*(const f16x8*)(a1p + 32), b1, acc1, 0, 0, 0);
        acc0 = __builtin_amdgcn_mfma_f32_16x16x32_f16(*(const f16x8*)(a0p + 64), b2, acc0, 0, 0, 0);
        acc1 = __builtin_amdgcn_mfma_f32_16x16x32_f16(*(const f16x8*)(a1p + 64), b2, acc1, 0, 0, 0);
        acc0 = __builtin_amdgcn_mfma_f32_16x16x32_f16(*(const f16x8*)(a0p + 96), b3, acc0, 0, 0, 0);
        acc1 = __builtin_amdgcn_mfma_f32_16x16x32_f16(*(const f16x8*)(a1p + 96), b3, acc1, 0, 0, 0);
    };

    // prologue: adj tiles 0,1 into slots 0,1
    int4 av0A = *(const int4*)(arow + j0);
    int4 av0B = *(const int4*)(arow + j0 + 4);
    int4 av1A = *(const int4*)(arow + 128 + j0);
    int4 av1B = *(const int4*)(arow + 128 + j0 + 4);

    __syncthreads();                 // s2s ready
    computeP(av0A, av0B, 0, 0);      // P(0) -> buf0
    __syncthreads();

    // main loop: 14 tiles, explicitly unrolled x2 (named slots; one barrier/tile)
    for (int tt = 0; tt < 14; tt += 2) {
        {   // tile tt: read buf0; write P(tt+1)->buf1; refill slot0 with tile tt+2
            const int tn = tt + 2;
            av0A = *(const int4*)(arow + tn * 128 + j0);
            av0B = *(const int4*)(arow + tn * 128 + j0 + 4);
            mmaTile(0, tt * 128);
            computeP(av1A, av1B, tt + 1, 1);
            __syncthreads();
        }
        {   // tile tt+1: read buf1; write P(tt+2)->buf0; refill slot1 with tile tt+3
            const int tn = tt + 3;
            av1A = *(const int4*)(arow + tn * 128 + j0);
            av1B = *(const int4*)(arow + tn * 128 + j0 + 4);
            mmaTile(1, (tt + 1) * 128);
            computeP(av0A, av0B, tt + 2, 0);
            __syncthreads();
        }
    }
    // epilogue: tiles 14, 15 (slots already hold them)
    mmaTile(0, 14 * 128);
    computeP(av1A, av1B, 15, 1);
    __syncthreads();
    mmaTile(1, 15 * 128);

    // ---- den: reduce 16 lanes per row ----
    denp += __shfl_xor(denp, 1, 64);
    denp += __shfl_xor(denp, 2, 64);
    denp += __shfl_xor(denp, 4, 64);
    denp += __shfl_xor(denp, 8, 64);
    if ((t & 15) == 0)
        den_g[(size_t)sp * N_ + rbase + r] = denp;

    // ---- num: unnormalized partial writes ----
    const int colg = 16 * w + ln15;
    const int rq   = lq * 4;
    #pragma unroll
    for (int q = 0; q < 4; ++q) {
        num_g[((size_t)sp * N_ + rbase + rq + q)      * FOUT + colg] = acc0[q];
        num_g[((size_t)sp * N_ + rbase + 16 + rq + q) * FOUT + colg] = acc1[q];
    }
}

// ---------------- Kernel 4: combine j-splits and normalize --------------------
__global__ __launch_bounds__(256) void k_norm(
    const float* __restrict__ num_g, const float* __restrict__ den_g,
    float* __restrict__ out)
{
    const int idx4 = blockIdx.x * 256 + threadIdx.x;
    const int i  = idx4 >> 5;
    const int c4 = (idx4 & 31) * 4;

    float4 s = {0.f, 0.f, 0.f, 0.f};
    float  d = 0.f;
    #pragma unroll
    for (int sp = 0; sp < 4; ++sp) {
        float4 v = *(const float4*)(num_g + ((size_t)sp * N_ + i) * FOUT + c4);
        s.x += v.x; s.y += v.y; s.z += v.z; s.w += v.w;
        d += den_g[(size_t)sp * N_ + i];
    }
    const float inv = 1.f / d;
    float4 o = {s.x * inv, s.y * inv, s.z * inv, s.w * inv};
    *(float4*)&out[(size_t)i * FOUT + c4] = o;
}

extern "C" void kernel_launch(void* const* d_in, const int* in_sizes, int n_in,
                              void* d_out, int out_size, void* d_ws, size_t ws_size,
                              hipStream_t stream) {
    const float* h   = (const float*)d_in[0];
    const int*   adj = (const int*)d_in[1];
    const float* W   = (const float*)d_in[2];
    const float* a   = (const float*)d_in[3];
    float* out = (float*)d_out;

    char* ws = (char*)d_ws;
    float*    Wh  = (float*)ws;                           // 4 MB
    _Float16* WhT = (_Float16*)(ws + (4u << 20));         // 2 MB
    float*    s1  = (float*)(ws + (6u << 20));            // 32 KB
    float*    s2  = (float*)(ws + (6u << 20) + 32768);    // 32 KB
    float*    num = (float*)(ws + (7u << 20));            // 16 MB
    float*    den = (float*)(ws + (23u << 20));           // 128 KB

    k_wh  <<<N_ / 2, 256, 0, stream>>>(h, W, a, Wh, s1, s2);
    k_tr  <<<N_ / 64, 256, 0, stream>>>(Wh, WhT);
    k_attn<<<1024, 512, 0, stream>>>(adj, WhT, s1, s2, num, den);
    k_norm<<<1024, 256, 0, stream>>>(num, den, out);
}

// Round 5
// 131.932 us; speedup vs baseline: 3.2912x; 1.0021x over previous
//
#include <hip/hip_runtime.h>

#define N_   8192
#define FIN  256
#define FOUT 128

typedef _Float16 f16x8 __attribute__((ext_vector_type(8)));
typedef _Float16 f16x4 __attribute__((ext_vector_type(4)));
typedef float    f32x4 __attribute__((ext_vector_type(4)));

// LDS-only barrier: waits for this wave's LDS ops, then s_barrier, WITHOUT
// draining vmcnt — global prefetches stay in flight across it. All vmem in
// k_attn is thread-private (regs), so no cross-thread vmem hazard exists.
#define LDS_BARRIER() asm volatile("s_waitcnt lgkmcnt(0)\n\ts_barrier" ::: "memory")

// ---------------- Kernel 1: Wh = h @ W, s1 = Wh@a1, s2 = Wh@a2 ----------------
// s1/s2 are pre-scaled by 1/ln2 so k_attn can use exp2 directly.
__global__ __launch_bounds__(256) void k_wh(
    const float* __restrict__ h, const float* __restrict__ W,
    const float* __restrict__ a, float* __restrict__ Wh,
    float* __restrict__ s1, float* __restrict__ s2)
{
    __shared__ float hrow[2][FIN];
    __shared__ float rbuf[2][2][2];
    const int t   = threadIdx.x;
    const int rh  = t >> 7;
    const int c   = t & 127;
    const int row = (blockIdx.x << 1) + rh;

    hrow[rh][c]       = h[(size_t)row * FIN + c];
    hrow[rh][c + 128] = h[(size_t)row * FIN + c + 128];
    __syncthreads();

    float acc = 0.f;
    #pragma unroll 8
    for (int k = 0; k < FIN; ++k)
        acc = fmaf(hrow[rh][k], W[k * FOUT + c], acc);

    Wh[(size_t)row * FOUT + c] = acc;

    float p1 = acc * a[c];
    float p2 = acc * a[FOUT + c];
    #pragma unroll
    for (int off = 32; off; off >>= 1) {
        p1 += __shfl_down(p1, off, 64);
        p2 += __shfl_down(p2, off, 64);
    }
    if ((t & 63) == 0) { rbuf[rh][c >> 6][0] = p1; rbuf[rh][c >> 6][1] = p2; }
    __syncthreads();
    if (c == 0) {
        const float k2 = 1.44269504088896f;  // 1/ln2
        s1[row] = (rbuf[rh][0][0] + rbuf[rh][1][0]) * k2;
        s2[row] = (rbuf[rh][0][1] + rbuf[rh][1][1]) * k2;
    }
}

// ---------------- Kernel 2: transpose+convert Wh -> WhT fp16 [128][8192] ------
__global__ __launch_bounds__(256) void k_tr(
    const float* __restrict__ Wh, _Float16* __restrict__ WhT)
{
    __shared__ float tile[64][129];
    const int t = threadIdx.x;
    const int rbase = blockIdx.x * 64;

    #pragma unroll
    for (int q = 0; q < 8; ++q) {
        int i4 = q * 256 + t;
        int r  = i4 >> 5;
        int c4 = (i4 & 31) * 4;
        *(float4*)&tile[r][c4] = *(const float4*)&Wh[(size_t)(rbase + r) * FOUT + c4];
    }
    __syncthreads();

    const int c = t >> 1, half = t & 1;
    _Float16 buf[32];
    #pragma unroll
    for (int r = 0; r < 32; ++r) buf[r] = (_Float16)tile[32 * half + r][c];
    #pragma unroll
    for (int q = 0; q < 4; ++q)
        *(f16x8*)&WhT[(size_t)c * N_ + rbase + 32 * half + 8 * q] = *(f16x8*)&buf[8 * q];
}

// ---------------- Kernel 3: fused masked-softmax numerator (MFMA) -------------
// Grid: 1024 = 256 row-blocks (32 rows) x 4 j-splits (2048 j each).
// Block: 512 thr = 8 waves; wave w owns output cols [16w,16w+16).
// One LDS-only barrier per 128-j tile; adj prefetch survives the barrier.
__global__ __launch_bounds__(512, 4) void k_attn(
    const int* __restrict__ adj, const _Float16* __restrict__ WhT,
    const float* __restrict__ s1g, const float* __restrict__ s2g,
    float* __restrict__ num_g, float* __restrict__ den_g)
{
    __shared__ _Float16 pA[2][32][136];   // 17 KB, padded: 272 B row stride
    __shared__ float s2s[2048];           // 8 KB

    const int t  = threadIdx.x;
    const int w  = t >> 6;
    const int l  = t & 63;

    const int rb    = blockIdx.x & 255;
    const int sp    = blockIdx.x >> 8;
    const int rbase = rb * 32;
    const int jbase = sp * 2048;

    // stage s2 slice (8 KB)
    *(float4*)&s2s[t * 4] = *(const float4*)&s2g[jbase + t * 4];

    // p-compute mapping: thread owns row r, 8 j's at j0
    const int r  = t >> 4;                 // 0..31
    const int j0 = (t & 15) << 3;          // 0..120
    const float s1r = s1g[rbase + r];
    const int* __restrict__ arow = adj + (size_t)(rbase + r) * N_ + jbase;

    // MFMA operand addressing
    const int ln15 = l & 15, lq = l >> 4;
    const _Float16* __restrict__ bptr =
        WhT + (size_t)(16 * w + ln15) * N_ + jbase + 8 * lq;

    f32x4 acc0 = {0.f, 0.f, 0.f, 0.f};
    f32x4 acc1 = {0.f, 0.f, 0.f, 0.f};
    float denp = 0.f;

    // phase-A: 8 attention weights -> fp16 LDS buffer `buf`.
    // p = exp2(lrelu(s1+s2) - 4/ln2)  (s1,s2 pre-scaled by 1/ln2)
    auto computeP = [&](const int4& aA, const int4& aB, int tile, int buf) {
        const float bias = -5.77078016f;   // -4/ln2
        const float* s2p = &s2s[tile * 128 + j0];
        float4 sA = *(const float4*)(s2p);
        float4 sB = *(const float4*)(s2p + 4);
        float m, e;
        f16x8 pv;
        m = s1r + sA.x; e = fmaxf(m, 0.2f * m); pv[0] = (_Float16)(aA.x ? __builtin_amdgcn_exp2f(e + bias) : 0.f);
        m = s1r + sA.y; e = fmaxf(m, 0.2f * m); pv[1] = (_Float16)(aA.y ? __builtin_amdgcn_exp2f(e + bias) : 0.f);
        m = s1r + sA.z; e = fmaxf(m, 0.2f * m); pv[2] = (_Float16)(aA.z ? __builtin_amdgcn_exp2f(e + bias) : 0.f);
        m = s1r + sA.w; e = fmaxf(m, 0.2f * m); pv[3] = (_Float16)(aA.w ? __builtin_amdgcn_exp2f(e + bias) : 0.f);
        m = s1r + sB.x; e = fmaxf(m, 0.2f * m); pv[4] = (_Float16)(aB.x ? __builtin_amdgcn_exp2f(e + bias) : 0.f);
        m = s1r + sB.y; e = fmaxf(m, 0.2f * m); pv[5] = (_Float16)(aB.y ? __builtin_amdgcn_exp2f(e + bias) : 0.f);
        m = s1r + sB.z; e = fmaxf(m, 0.2f * m); pv[6] = (_Float16)(aB.z ? __builtin_amdgcn_exp2f(e + bias) : 0.f);
        m = s1r + sB.w; e = fmaxf(m, 0.2f * m); pv[7] = (_Float16)(aB.w ? __builtin_amdgcn_exp2f(e + bias) : 0.f);
        denp += (float)pv[0] + (float)pv[1] + (float)pv[2] + (float)pv[3]
              + (float)pv[4] + (float)pv[5] + (float)pv[6] + (float)pv[7];
        *(f16x8*)&pA[buf][r][j0] = pv;
    };

    // phase-B: 8 MFMAs over one 128-j tile from LDS buffer `buf`
    auto mmaTile = [&](int buf, int jb) {
        f16x8 b0 = *(const f16x8*)(bptr + jb);
        f16x8 b1 = *(const f16x8*)(bptr + jb + 32);
        f16x8 b2 = *(const f16x8*)(bptr + jb + 64);
        f16x8 b3 = *(const f16x8*)(bptr + jb + 96);
        const _Float16* a0p = &pA[buf][ln15][8 * lq];
        const _Float16* a1p = &pA[buf][16 + ln15][8 * lq];
        acc0 = __builtin_amdgcn_mfma_f32_16x16x32_f16(*(const f16x8*)(a0p),      b0, acc0, 0, 0, 0);
        acc1 = __builtin_amdgcn_mfma_f32_16x16x32_f16(*(const f16x8*)(a1p),      b0, acc1, 0, 0, 0);
        acc0 = __builtin_amdgcn_mfma_f32_16x16x32_f16(*(const f16x8*)(a0p + 32), b1, acc0, 0, 0, 0);
        acc1 = __builtin_amdgcn_mfma_f32_16x16x32_f16(*(const f16x8*)(a1p + 32), b1, acc1, 0, 0, 0);
        acc0 = __builtin_amdgcn_mfma_f32_16x16x32_f16(*(const f16x8*)(a0p + 64), b2, acc0, 0, 0, 0);
        acc1 = __builtin_amdgcn_mfma_f32_16x16x32_f16(*(const f16x8*)(a1p + 64), b2, acc1, 0, 0, 0);
        acc0 = __builtin_amdgcn_mfma_f32_16x16x32_f16(*(const f16x8*)(a0p + 96), b3, acc0, 0, 0, 0);
        acc1 = __builtin_amdgcn_mfma_f32_16x16x32_f16(*(const f16x8*)(a1p + 96), b3, acc1, 0, 0, 0);
    };

    // prologue: adj tiles 0,1 into slots 0,1
    int4 av0A = *(const int4*)(arow + j0);
    int4 av0B = *(const int4*)(arow + j0 + 4);
    int4 av1A = *(const int4*)(arow + 128 + j0);
    int4 av1B = *(const int4*)(arow + 128 + j0 + 4);

    LDS_BARRIER();                   // s2s ready
    computeP(av0A, av0B, 0, 0);      // P(0) -> buf0
    LDS_BARRIER();

    // main loop: 14 tiles, explicitly unrolled x2 (one barrier per tile)
    for (int tt = 0; tt < 14; tt += 2) {
        {   // tile tt: read buf0; write P(tt+1)->buf1; refill slot0 with tile tt+2
            const int tn = tt + 2;
            av0A = *(const int4*)(arow + tn * 128 + j0);
            av0B = *(const int4*)(arow + tn * 128 + j0 + 4);
            mmaTile(0, tt * 128);
            computeP(av1A, av1B, tt + 1, 1);
            LDS_BARRIER();
        }
        {   // tile tt+1: read buf1; write P(tt+2)->buf0; refill slot1 with tile tt+3
            const int tn = tt + 3;
            av1A = *(const int4*)(arow + tn * 128 + j0);
            av1B = *(const int4*)(arow + tn * 128 + j0 + 4);
            mmaTile(1, (tt + 1) * 128);
            computeP(av0A, av0B, tt + 2, 0);
            LDS_BARRIER();
        }
    }
    // epilogue: tiles 14, 15 (slots already hold them)
    mmaTile(0, 14 * 128);
    computeP(av1A, av1B, 15, 1);
    LDS_BARRIER();
    mmaTile(1, 15 * 128);

    // ---- den: reduce 16 lanes per row ----
    denp += __shfl_xor(denp, 1, 64);
    denp += __shfl_xor(denp, 2, 64);
    denp += __shfl_xor(denp, 4, 64);
    denp += __shfl_xor(denp, 8, 64);
    if ((t & 15) == 0)
        den_g[(size_t)sp * N_ + rbase + r] = denp;

    // ---- num: unnormalized partial writes ----
    const int colg = 16 * w + ln15;
    const int rq   = lq * 4;
    #pragma unroll
    for (int q = 0; q < 4; ++q) {
        num_g[((size_t)sp * N_ + rbase + rq + q)      * FOUT + colg] = acc0[q];
        num_g[((size_t)sp * N_ + rbase + 16 + rq + q) * FOUT + colg] = acc1[q];
    }
}

// ---------------- Kernel 4: combine j-splits and normalize --------------------
__global__ __launch_bounds__(256) void k_norm(
    const float* __restrict__ num_g, const float* __restrict__ den_g,
    float* __restrict__ out)
{
    const int idx4 = blockIdx.x * 256 + threadIdx.x;
    const int i  = idx4 >> 5;
    const int c4 = (idx4 & 31) * 4;

    float4 s = {0.f, 0.f, 0.f, 0.f};
    float  d = 0.f;
    #pragma unroll
    for (int sp = 0; sp < 4; ++sp) {
        float4 v = *(const float4*)(num_g + ((size_t)sp * N_ + i) * FOUT + c4);
        s.x += v.x; s.y += v.y; s.z += v.z; s.w += v.w;
        d += den_g[(size_t)sp * N_ + i];
    }
    const float inv = 1.f / d;
    float4 o = {s.x * inv, s.y * inv, s.z * inv, s.w * inv};
    *(float4*)&out[(size_t)i * FOUT + c4] = o;
}

extern "C" void kernel_launch(void* const* d_in, const int* in_sizes, int n_in,
                              void* d_out, int out_size, void* d_ws, size_t ws_size,
                              hipStream_t stream) {
    const float* h   = (const float*)d_in[0];
    const int*   adj = (const int*)d_in[1];
    const float* W   = (const float*)d_in[2];
    const float* a   = (const float*)d_in[3];
    float* out = (float*)d_out;

    char* ws = (char*)d_ws;
    float*    Wh  = (float*)ws;                           // 4 MB
    _Float16* WhT = (_Float16*)(ws + (4u << 20));         // 2 MB
    float*    s1  = (float*)(ws + (6u << 20));            // 32 KB
    float*    s2  = (float*)(ws + (6u << 20) + 32768);    // 32 KB
    float*    num = (float*)(ws + (7u << 20));            // 16 MB
    float*    den = (float*)(ws + (23u << 20));           // 128 KB

    k_wh  <<<N_ / 2, 256, 0, stream>>>(h, W, a, Wh, s1, s2);
    k_tr  <<<N_ / 64, 256, 0, stream>>>(Wh, WhT);
    k_attn<<<1024, 512, 0, stream>>>(adj, WhT, s1, s2, num, den);
    k_norm<<<1024, 256, 0, stream>>>(num, den, out);
}